// Round 6
// baseline (617.345 us; speedup 1.0000x reference)
//
#include <hip/hip_runtime.h>

#define HD 64
#define BN_EPS 1e-5f

typedef __attribute__((ext_vector_type(8))) short bfrag;
typedef __attribute__((ext_vector_type(4))) float ffrag;

__device__ __forceinline__ unsigned tobf(float x) {
    unsigned u = __float_as_uint(x);
    return (u + 0x7fffu + ((u >> 16) & 1u)) >> 16;
}
__device__ __forceinline__ float bf_lo(unsigned u) { return __uint_as_float(u << 16); }
__device__ __forceinline__ float bf_hi(unsigned u) { return __uint_as_float(u & 0xffff0000u); }

// ---------- CSR construction (rows padded to 16: slot0=self, pads->node N) ----------

__global__ void k_deg(const int* __restrict__ dst, int* __restrict__ deg, int E) {
    int e = blockIdx.x * blockDim.x + threadIdx.x;
    if (e < E) atomicAdd(&deg[dst[e]], 1);
}

// inclusive scan of padded degree (256/block) + dinv + hWs zero-row init
__global__ void k_scan1(const int* __restrict__ deg, int* __restrict__ incl,
                        int* __restrict__ bsums, float* __restrict__ dinv,
                        unsigned* __restrict__ hWs, int N) {
    __shared__ int s[256];
    int tid = threadIdx.x;
    int i = blockIdx.x * 256 + tid;
    if (blockIdx.x == 0 && tid < 32) hWs[(size_t)N * 32 + tid] = 0u;  // zero row
    int d = (i < N) ? deg[i] : 0;
    int pd = (i < N) ? ((d + 16) & ~15) : 0;  // roundup(deg+1, 16)
    s[tid] = pd;
    __syncthreads();
    for (int off = 1; off < 256; off <<= 1) {
        int t = (tid >= off) ? s[tid - off] : 0;
        __syncthreads();
        s[tid] += t;
        __syncthreads();
    }
    if (i < N) {
        incl[i] = s[tid];
        dinv[i] = rsqrtf((float)(d + 1));
    }
    if (tid == 255) bsums[blockIdx.x] = s[255];
}

// rowp from incl + per-block prefix of bsums; self edge in slot0, pads -> N
__global__ void k_scan3(int* __restrict__ rowp, const int* __restrict__ deg,
                        const int* __restrict__ incl, const int* __restrict__ bsums,
                        int* __restrict__ ed, int N, int nb) {
    __shared__ float red[256];
    int tid = threadIdx.x;
    int b = blockIdx.x;
    float psum = 0.f;
    for (int t = tid; t < b; t += 256) psum += (float)bsums[t];
    red[tid] = psum;
    __syncthreads();
    for (int off = 128; off > 0; off >>= 1) {
        if (tid < off) red[tid] += red[tid + off];
        __syncthreads();
    }
    int bpre = (int)red[0];
    int i = b * 256 + tid;
    if (i < N) {
        int d = deg[i];
        int pd = (d + 16) & ~15;
        int rv = incl[i] - pd + bpre;  // exclusive global offset
        rowp[i] = rv;
        ed[rv] = i;  // self edge in slot 0
        for (int k = d + 1; k < pd; k++) ed[rv + k] = N;  // pads -> zero row
        if (i == N - 1) rowp[N] = rv + pd;
    }
}

// bucket edges into CSR slots (offset by 1 for self) + per-graph counts fused
__global__ void k_fill(const int* __restrict__ src, const int* __restrict__ dst,
                       const int* __restrict__ rowp, int* __restrict__ cur,
                       int* __restrict__ ed, const int* __restrict__ batch,
                       int* __restrict__ cnt, int E, int N, int G) {
    int e = blockIdx.x * blockDim.x + threadIdx.x;
    if (e < G) {
        int g = e;
        int lo = 0, hi = N;
        while (lo < hi) { int mid = (lo + hi) >> 1; if (batch[mid] < g) lo = mid + 1; else hi = mid; }
        int lo2 = lo, hi2 = N;
        while (lo2 < hi2) { int mid = (lo2 + hi2) >> 1; if (batch[mid] < g + 1) lo2 = mid + 1; else hi2 = mid; }
        cnt[g] = lo2 - lo;
    }
    if (e >= E) return;
    int d = dst[e];
    int pos = rowp[d] + 1 + atomicAdd(&cur[d], 1);
    ed[pos] = src[e];
}

// ---------- MFMA gemm: hWs[i][f] = bf16( dinv[i]*(sum_k A[i][k]*W[f][k] + cb[f]) ) ----------
template<int FP32IN>
__global__ __launch_bounds__(256) void k_gemm2(const void* __restrict__ Aptr,
                                               const void* __restrict__ Wptr,
                                               const float* __restrict__ cb,
                                               const float* __restrict__ dinv,
                                               unsigned short* __restrict__ hWs,
                                               int N, int ntiles) {
    int lane = threadIdx.x & 63;
    int m = lane & 15, quad = lane >> 4;
    bfrag wf[4][2];
    if (FP32IN) {
        const float* W = (const float*)Wptr;
#pragma unroll
        for (int ft = 0; ft < 4; ft++)
#pragma unroll
            for (int kf = 0; kf < 2; kf++) {
                const float4* p4 = (const float4*)(W + (ft * 16 + m) * HD + kf * 32 + quad * 8);
                float4 x0 = p4[0], x1 = p4[1];
                union { unsigned u[4]; bfrag b; } r;
                r.u[0] = tobf(x0.x) | (tobf(x0.y) << 16);
                r.u[1] = tobf(x0.z) | (tobf(x0.w) << 16);
                r.u[2] = tobf(x1.x) | (tobf(x1.y) << 16);
                r.u[3] = tobf(x1.z) | (tobf(x1.w) << 16);
                wf[ft][kf] = r.b;
            }
    } else {
        const unsigned short* W = (const unsigned short*)Wptr;
#pragma unroll
        for (int ft = 0; ft < 4; ft++)
#pragma unroll
            for (int kf = 0; kf < 2; kf++)
                wf[ft][kf] = *(const bfrag*)(W + (ft * 16 + m) * HD + kf * 32 + quad * 8);
    }
    float cbv[4];
#pragma unroll
    for (int ft = 0; ft < 4; ft++) cbv[ft] = cb ? cb[ft * 16 + m] : 0.f;

    int wid = (blockIdx.x * blockDim.x + threadIdx.x) >> 6;
    int nw = (gridDim.x * blockDim.x) >> 6;
    for (int tile = wid; tile < ntiles; tile += nw) {
        int arow = min(tile * 16 + m, N - 1);
        bfrag a0, a1;
        if (FP32IN) {
            const float4* p4 = (const float4*)((const float*)Aptr + (size_t)arow * HD + quad * 8);
            float4 x0 = p4[0], x1 = p4[1], y0 = p4[8], y1 = p4[9];
            union { unsigned u[4]; bfrag b; } r0, r1;
            r0.u[0] = tobf(x0.x) | (tobf(x0.y) << 16);
            r0.u[1] = tobf(x0.z) | (tobf(x0.w) << 16);
            r0.u[2] = tobf(x1.x) | (tobf(x1.y) << 16);
            r0.u[3] = tobf(x1.z) | (tobf(x1.w) << 16);
            r1.u[0] = tobf(y0.x) | (tobf(y0.y) << 16);
            r1.u[1] = tobf(y0.z) | (tobf(y0.w) << 16);
            r1.u[2] = tobf(y1.x) | (tobf(y1.y) << 16);
            r1.u[3] = tobf(y1.z) | (tobf(y1.w) << 16);
            a0 = r0.b; a1 = r1.b;
        } else {
            const unsigned short* p = (const unsigned short*)Aptr + (size_t)arow * HD + quad * 8;
            a0 = *(const bfrag*)p;
            a1 = *(const bfrag*)(p + 32);
        }
        ffrag acc[4];
#pragma unroll
        for (int ft = 0; ft < 4; ft++) {
            acc[ft] = (ffrag){0.f, 0.f, 0.f, 0.f};
            acc[ft] = __builtin_amdgcn_mfma_f32_16x16x32_bf16(a0, wf[ft][0], acc[ft], 0, 0, 0);
            acc[ft] = __builtin_amdgcn_mfma_f32_16x16x32_bf16(a1, wf[ft][1], acc[ft], 0, 0, 0);
        }
        int r0n = tile * 16 + quad * 4;
        float dv[4];
#pragma unroll
        for (int r = 0; r < 4; r++) dv[r] = dinv[min(r0n + r, N - 1)];
#pragma unroll
        for (int ft = 0; ft < 4; ft++)
#pragma unroll
            for (int r = 0; r < 4; r++) {
                int nrow = r0n + r;
                if (nrow < N) {
                    float v = (acc[ft][r] + cbv[ft]) * dv[r];
                    hWs[(size_t)nrow * HD + ft * 16 + m] = (unsigned short)tobf(v);
                }
            }
    }
}

// ---------- aggregation: dwordx4 gathers (8 rows/instr, 2 instrs per 16-slot
// group), direct per-lane edge-id loads (no shfl staging), per-node xor-reduce.
// lane: q=lane>>3 selects row within group, m8=lane&7 selects 16B feat chunk. ----------
__global__ __launch_bounds__(256) void k_agg(const int* __restrict__ rowp,
                                             const int* __restrict__ ed,
                                             const float* __restrict__ dinv,
                                             const unsigned* __restrict__ hWs,
                                             const float* __restrict__ bias,
                                             const int* __restrict__ batch,
                                             void* __restrict__ outp, int outBf,
                                             float* __restrict__ stats,
                                             float* __restrict__ praw,
                                             int N, int chunk,
                                             const float* __restrict__ gam,
                                             const float* __restrict__ bet,
                                             float* __restrict__ ss,
                                             const float* __restrict__ Wnext,
                                             unsigned* __restrict__ Wfb,
                                             float* __restrict__ cf,
                                             float invN, int* __restrict__ ticket) {
    int tid = threadIdx.x;
    int lane = tid & 63;
    int q = lane >> 3;     // row group 0..7
    int m8 = lane & 7;     // 16B chunk within row
    int wid = blockIdx.x * 4 + (tid >> 6);
    int i0 = wid * chunk, i1 = min(i0 + chunk, N);
    float bv[8];
    {
        const float4* bp = (const float4*)(bias + m8 * 8);
        float4 t0 = bp[0], t1 = bp[1];
        bv[0] = t0.x; bv[1] = t0.y; bv[2] = t0.z; bv[3] = t0.w;
        bv[4] = t1.x; bv[5] = t1.y; bv[6] = t1.z; bv[7] = t1.w;
    }
    float bs[8], bq[8], p[8];
#pragma unroll
    for (int k = 0; k < 8; k++) { bs[k] = 0.f; bq[k] = 0.f; p[k] = 0.f; }
    int curb = -1;
    for (int i = i0; i < i1; i++) {
        int rs = rowp[i];
        int ng = (rowp[i + 1] - rs) >> 4;
        float acc[8];
#pragma unroll
        for (int k = 0; k < 8; k++) acc[k] = 0.f;
        for (int g = 0; g < ng; g++) {
            int sb = rs + (g << 4);
            int e0 = ed[sb + q];
            int e1 = ed[sb + 8 + q];
            uint4 ua = *(const uint4*)(hWs + (size_t)e0 * 32 + m8 * 4);
            uint4 ub = *(const uint4*)(hWs + (size_t)e1 * 32 + m8 * 4);
            acc[0] += bf_lo(ua.x) + bf_lo(ub.x);
            acc[1] += bf_hi(ua.x) + bf_hi(ub.x);
            acc[2] += bf_lo(ua.y) + bf_lo(ub.y);
            acc[3] += bf_hi(ua.y) + bf_hi(ub.y);
            acc[4] += bf_lo(ua.z) + bf_lo(ub.z);
            acc[5] += bf_hi(ua.z) + bf_hi(ub.z);
            acc[6] += bf_lo(ua.w) + bf_lo(ub.w);
            acc[7] += bf_hi(ua.w) + bf_hi(ub.w);
        }
#pragma unroll
        for (int k = 0; k < 8; k++) {
            acc[k] += __shfl_xor(acc[k], 8);
            acc[k] += __shfl_xor(acc[k], 16);
            acc[k] += __shfl_xor(acc[k], 32);
        }
        float di = dinv[i];
        int b = batch[i];
        float h[8];
#pragma unroll
        for (int k = 0; k < 8; k++) h[k] = fmaxf(fmaf(di, acc[k], bv[k]), 0.f);
        if (q == 0) {
            if (outBf) {
                uint4 o;
                o.x = tobf(h[0]) | (tobf(h[1]) << 16);
                o.y = tobf(h[2]) | (tobf(h[3]) << 16);
                o.z = tobf(h[4]) | (tobf(h[5]) << 16);
                o.w = tobf(h[6]) | (tobf(h[7]) << 16);
                ((uint4*)outp)[(size_t)i * 8 + m8] = o;
            } else {
                ((float4*)outp)[(size_t)i * 16 + m8 * 2] = make_float4(h[0], h[1], h[2], h[3]);
                ((float4*)outp)[(size_t)i * 16 + m8 * 2 + 1] = make_float4(h[4], h[5], h[6], h[7]);
            }
#pragma unroll
            for (int k = 0; k < 8; k++) {
                bs[k] += h[k];
                bq[k] = fmaf(h[k], h[k], bq[k]);
            }
            if (b != curb) {
                if (curb >= 0) {
#pragma unroll
                    for (int k = 0; k < 8; k++)
                        atomicAdd(&praw[(size_t)curb * HD + m8 * 8 + k], p[k]);
                }
                curb = b;
#pragma unroll
                for (int k = 0; k < 8; k++) p[k] = h[k];
            } else {
#pragma unroll
                for (int k = 0; k < 8; k++) p[k] += h[k];
            }
        }
    }
    if (q == 0 && curb >= 0) {
#pragma unroll
        for (int k = 0; k < 8; k++)
            atomicAdd(&praw[(size_t)curb * HD + m8 * 8 + k], p[k]);
    }
    __shared__ float r1s[4][HD], r2s[4][HD];
    int wv = tid >> 6;
    if (q == 0) {
#pragma unroll
        for (int k = 0; k < 8; k++) {
            r1s[wv][m8 * 8 + k] = bs[k];
            r2s[wv][m8 * 8 + k] = bq[k];
        }
    }
    __syncthreads();
    if (tid < HD) {
        atomicAdd(&stats[tid], r1s[0][tid] + r1s[1][tid] + r1s[2][tid] + r1s[3][tid]);
        atomicAdd(&stats[HD + tid], r2s[0][tid] + r2s[1][tid] + r2s[2][tid] + r2s[3][tid]);
    }
    // ---- last block: BN finalize + fold into next layer's weights ----
    __shared__ int lastFlag;
    __syncthreads();
    if (tid == 0) {
        __threadfence();
        lastFlag = (atomicAdd(ticket, 1) == (int)gridDim.x - 1) ? 1 : 0;
    }
    __syncthreads();
    if (lastFlag) {
        __shared__ float lss[128];
        if (tid < HD) {
            float s1v = atomicAdd(&stats[tid], 0.f);
            float s2v = atomicAdd(&stats[HD + tid], 0.f);
            float mean = s1v * invN;
            float var = s2v * invN - mean * mean;
            float sc = gam[tid] * rsqrtf(var + BN_EPS);
            float sh = bet[tid] - mean * sc;
            ss[tid] = sc; ss[64 + tid] = sh;
            lss[tid] = sc; lss[64 + tid] = sh;
        }
        __syncthreads();
        if (Wnext && tid < HD) {
            float c = 0.f;
            for (int qq = 0; qq < 32; qq++) {
                float wa = Wnext[tid * HD + 2 * qq];
                float wb = Wnext[tid * HD + 2 * qq + 1];
                Wfb[tid * 32 + qq] = tobf(wa * lss[2 * qq]) | (tobf(wb * lss[2 * qq + 1]) << 16);
                c = fmaf(lss[64 + 2 * qq], wa, c);
                c = fmaf(lss[64 + 2 * qq + 1], wb, c);
            }
            cf[tid] = c;
        }
    }
}

// fused: normalize final h in place (float4) + pool finalize
__global__ __launch_bounds__(256) void k_fin(float* __restrict__ h,
                                             const float* __restrict__ ss_all,
                                             const float* __restrict__ praw,
                                             const int* __restrict__ cnt,
                                             float* __restrict__ pool,
                                             int nquads, int G) {
    int nb1 = (nquads + 255) >> 8;
    if ((int)blockIdx.x < nb1) {
        int idx = blockIdx.x * 256 + threadIdx.x;
        if (idx >= nquads) return;
        const float* ss = ss_all + 2 * 128;
        float4* h4 = (float4*)h;
        float4 v = h4[idx];
        int f0 = (idx * 4) & 63;
        v.x = fmaf(v.x, ss[f0 + 0], ss[64 + f0 + 0]);
        v.y = fmaf(v.y, ss[f0 + 1], ss[64 + f0 + 1]);
        v.z = fmaf(v.z, ss[f0 + 2], ss[64 + f0 + 2]);
        v.w = fmaf(v.w, ss[f0 + 3], ss[64 + f0 + 3]);
        h4[idx] = v;
    } else {
        int idx = (blockIdx.x - nb1) * 256 + threadIdx.x;
        if (idx >= G * 192) return;
        int g = idx / 192;
        int r = idx - g * 192;
        int l = r >> 6;
        int f = r & 63;
        const float* ss = ss_all + l * 128;
        float v = praw[((size_t)l * G + g) * HD + f];
        pool[idx] = fmaf(ss[f], v, (float)cnt[g] * ss[64 + f]);
    }
}

extern "C" void kernel_launch(void* const* d_in, const int* in_sizes, int n_in,
                              void* d_out, int out_size, void* d_ws, size_t ws_size,
                              hipStream_t stream) {
    const int N = in_sizes[0] / HD;             // 100000
    const int E = in_sizes[1] / 2;              // 1000000
    const int G = (out_size - N * HD) / 192;    // 512

    const float* x = (const float*)d_in[0];
    const int* ei = (const int*)d_in[1];
    const int* srcA = ei;
    const int* dstA = ei + E;
    const int* batch = (const int*)d_in[2];
    const float* W[3]    = {(const float*)d_in[3], (const float*)d_in[7],  (const float*)d_in[11]};
    const float* bias[3] = {(const float*)d_in[4], (const float*)d_in[8],  (const float*)d_in[12]};
    const float* gam[3]  = {(const float*)d_in[5], (const float*)d_in[9],  (const float*)d_in[13]};
    const float* bet[3]  = {(const float*)d_in[6], (const float*)d_in[10], (const float*)d_in[14]};

    char* ws = (char*)d_ws;
    size_t off = 0;
    auto alloc = [&](size_t bytes) -> void* {
        void* p = ws + off;
        off = (off + bytes + 255) & ~(size_t)255;
        return p;
    };
    // zero-region (single memset): deg, cur, stats, tickets, praw
    int* deg     = (int*)alloc((size_t)N * 4);
    int* cur     = (int*)alloc((size_t)N * 4);
    float* stats = (float*)alloc(3 * 128 * 4);
    int* tickets = (int*)alloc(3 * 4);
    float* praw  = (float*)alloc((size_t)3 * G * HD * 4);
    size_t zbytes = off;
    float* dinv  = (float*)alloc((size_t)N * 4);
    int* rowp    = (int*)alloc((size_t)(N + 1) * 4);
    int* incl    = (int*)alloc((size_t)N * 4);
    int* bsums   = (int*)alloc(512 * 4);
    int* ed      = (int*)alloc(((size_t)E + 16 * (size_t)N) * 4 + 512);
    unsigned short* hWs  = (unsigned short*)alloc((size_t)(N + 1) * HD * 2);
    unsigned short* hraw = (unsigned short*)alloc((size_t)N * HD * 2);
    float* ss    = (float*)alloc(3 * 128 * 4);
    unsigned* Wfb = (unsigned*)alloc(2 * HD * 32 * 4);
    float* cf    = (float*)alloc(2 * HD * 4);
    int* gcnt    = (int*)alloc((size_t)G * 4);
    (void)ws_size;

    float* pool = (float*)d_out;                      // [G,192]
    float* hbuf = (float*)d_out + (size_t)G * 192;    // [N,64] final h (fp32)

    hipMemsetAsync(deg, 0, zbytes, stream);

    int nb = (N + 255) / 256;
    k_deg<<<(E + 255) / 256, 256, 0, stream>>>(dstA, deg, E);
    k_scan1<<<nb, 256, 0, stream>>>(deg, incl, bsums, dinv, (unsigned*)hWs, N);
    k_scan3<<<nb, 256, 0, stream>>>(rowp, deg, incl, bsums, ed, N, nb);
    k_fill<<<(E + 255) / 256, 256, 0, stream>>>(srcA, dstA, rowp, cur, ed, batch, gcnt, E, N, G);

    const int AGG_BLOCKS = 2048;
    const int NW = AGG_BLOCKS * 4;
    const int chunk = (N + NW - 1) / NW;
    const int ntiles = (N + 15) / 16;

    for (int l = 0; l < 3; l++) {
        if (l == 0)
            k_gemm2<1><<<640, 256, 0, stream>>>(x, W[0], nullptr, dinv, hWs, N, ntiles);
        else
            k_gemm2<0><<<640, 256, 0, stream>>>(hraw, Wfb + (size_t)(l - 1) * HD * 32,
                                                cf + (l - 1) * HD, dinv, hWs, N, ntiles);
        void* outp = (l < 2) ? (void*)hraw : (void*)hbuf;
        k_agg<<<AGG_BLOCKS, 256, 0, stream>>>(rowp, ed, dinv, (const unsigned*)hWs,
                                              bias[l], batch, outp, (l < 2) ? 1 : 0,
                                              stats + l * 128, praw + (size_t)l * G * HD,
                                              N, chunk,
                                              gam[l], bet[l], ss + l * 128,
                                              (l < 2) ? W[l + 1] : nullptr,
                                              Wfb + (size_t)(l < 2 ? l : 0) * HD * 32,
                                              cf + (l < 2 ? l : 0) * HD,
                                              1.0f / (float)N, tickets + l);
    }
    int nquads = N * HD / 4;
    int nb1 = (nquads + 255) / 256;
    int nb2 = (G * 192 + 255) / 256;
    k_fin<<<nb1 + nb2, 256, 0, stream>>>(hbuf, ss, praw, gcnt, pool, nquads, G);
}

// Round 7
// 553.744 us; speedup vs baseline: 1.1149x; 1.1149x over previous
//
#include <hip/hip_runtime.h>

#define HD 64
#define BN_EPS 1e-5f
#define NWAVES 8192

typedef __attribute__((ext_vector_type(8))) short bfrag;
typedef __attribute__((ext_vector_type(4))) float ffrag;

__device__ __forceinline__ unsigned tobf(float x) {
    unsigned u = __float_as_uint(x);
    return (u + 0x7fffu + ((u >> 16) & 1u)) >> 16;
}
__device__ __forceinline__ float bf_lo(unsigned u) { return __uint_as_float(u << 16); }
__device__ __forceinline__ float bf_hi(unsigned u) { return __uint_as_float(u & 0xffff0000u); }

// ---------- CSR construction (rows padded to 8: slot0=self, pads->node N) ----------

__global__ void k_deg(const int* __restrict__ dst, int* __restrict__ deg, int E) {
    int e = blockIdx.x * blockDim.x + threadIdx.x;
    if (e < E) atomicAdd(&deg[dst[e]], 1);
}

// inclusive scan of padded degree (256/block) + dinv + hWs zero-row init
__global__ void k_scan1(const int* __restrict__ deg, int* __restrict__ incl,
                        int* __restrict__ bsums, float* __restrict__ dinv,
                        unsigned* __restrict__ hWs, int N) {
    __shared__ int s[256];
    int tid = threadIdx.x;
    int i = blockIdx.x * 256 + tid;
    if (blockIdx.x == 0 && tid < 32) hWs[(size_t)N * 32 + tid] = 0u;  // zero row
    int d = (i < N) ? deg[i] : 0;
    int pd = (i < N) ? ((d + 8) & ~7) : 0;  // roundup(deg+1, 8)
    s[tid] = pd;
    __syncthreads();
    for (int off = 1; off < 256; off <<= 1) {
        int t = (tid >= off) ? s[tid - off] : 0;
        __syncthreads();
        s[tid] += t;
        __syncthreads();
    }
    if (i < N) {
        incl[i] = s[tid];
        dinv[i] = rsqrtf((float)(d + 1));
    }
    if (tid == 255) bsums[blockIdx.x] = s[255];
}

// rowp from incl + per-block prefix of bsums; self edge in slot0, pads -> N
__global__ void k_scan3(int* __restrict__ rowp, const int* __restrict__ deg,
                        const int* __restrict__ incl, const int* __restrict__ bsums,
                        int* __restrict__ ed, int N, int nb) {
    __shared__ float red[256];
    int tid = threadIdx.x;
    int b = blockIdx.x;
    float psum = 0.f;
    for (int t = tid; t < b; t += 256) psum += (float)bsums[t];
    red[tid] = psum;
    __syncthreads();
    for (int off = 128; off > 0; off >>= 1) {
        if (tid < off) red[tid] += red[tid + off];
        __syncthreads();
    }
    int bpre = (int)red[0];
    int i = b * 256 + tid;
    if (i < N) {
        int d = deg[i];
        int pd = (d + 8) & ~7;
        int rv = incl[i] - pd + bpre;  // exclusive global offset
        rowp[i] = rv;
        ed[rv] = i;  // self edge in slot 0
        for (int k = d + 1; k < pd; k++) ed[rv + k] = N;  // pads -> zero row
        if (i == N - 1) rowp[N] = rv + pd;
    }
}

// bucket edges into CSR slots (offset by 1 for self) + per-graph counts fused
__global__ void k_fill(const int* __restrict__ src, const int* __restrict__ dst,
                       const int* __restrict__ rowp, int* __restrict__ cur,
                       int* __restrict__ ed, const int* __restrict__ batch,
                       int* __restrict__ cnt, int E, int N, int G) {
    int e = blockIdx.x * blockDim.x + threadIdx.x;
    if (e < G) {
        int g = e;
        int lo = 0, hi = N;
        while (lo < hi) { int mid = (lo + hi) >> 1; if (batch[mid] < g) lo = mid + 1; else hi = mid; }
        int lo2 = lo, hi2 = N;
        while (lo2 < hi2) { int mid = (lo2 + hi2) >> 1; if (batch[mid] < g + 1) lo2 = mid + 1; else hi2 = mid; }
        cnt[g] = lo2 - lo;
    }
    if (e >= E) return;
    int d = dst[e];
    int pos = rowp[d] + 1 + atomicAdd(&cur[d], 1);
    ed[pos] = src[e];
}

// ---------- MFMA gemm: hWs[i][f] = bf16( dinv[i]*(sum_k A[i][k]*W[f][k] + cb[f]) ) ----------
template<int FP32IN>
__global__ __launch_bounds__(256) void k_gemm2(const void* __restrict__ Aptr,
                                               const void* __restrict__ Wptr,
                                               const float* __restrict__ cb,
                                               const float* __restrict__ dinv,
                                               unsigned short* __restrict__ hWs,
                                               int N, int ntiles) {
    int lane = threadIdx.x & 63;
    int m = lane & 15, quad = lane >> 4;
    bfrag wf[4][2];
    if (FP32IN) {
        const float* W = (const float*)Wptr;
#pragma unroll
        for (int ft = 0; ft < 4; ft++)
#pragma unroll
            for (int kf = 0; kf < 2; kf++) {
                const float4* p4 = (const float4*)(W + (ft * 16 + m) * HD + kf * 32 + quad * 8);
                float4 x0 = p4[0], x1 = p4[1];
                union { unsigned u[4]; bfrag b; } r;
                r.u[0] = tobf(x0.x) | (tobf(x0.y) << 16);
                r.u[1] = tobf(x0.z) | (tobf(x0.w) << 16);
                r.u[2] = tobf(x1.x) | (tobf(x1.y) << 16);
                r.u[3] = tobf(x1.z) | (tobf(x1.w) << 16);
                wf[ft][kf] = r.b;
            }
    } else {
        const unsigned short* W = (const unsigned short*)Wptr;
#pragma unroll
        for (int ft = 0; ft < 4; ft++)
#pragma unroll
            for (int kf = 0; kf < 2; kf++)
                wf[ft][kf] = *(const bfrag*)(W + (ft * 16 + m) * HD + kf * 32 + quad * 8);
    }
    float cbv[4];
#pragma unroll
    for (int ft = 0; ft < 4; ft++) cbv[ft] = cb ? cb[ft * 16 + m] : 0.f;

    int wid = (blockIdx.x * blockDim.x + threadIdx.x) >> 6;
    int nw = (gridDim.x * blockDim.x) >> 6;
    for (int tile = wid; tile < ntiles; tile += nw) {
        int arow = min(tile * 16 + m, N - 1);
        bfrag a0, a1;
        if (FP32IN) {
            const float4* p4 = (const float4*)((const float*)Aptr + (size_t)arow * HD + quad * 8);
            float4 x0 = p4[0], x1 = p4[1], y0 = p4[8], y1 = p4[9];
            union { unsigned u[4]; bfrag b; } r0, r1;
            r0.u[0] = tobf(x0.x) | (tobf(x0.y) << 16);
            r0.u[1] = tobf(x0.z) | (tobf(x0.w) << 16);
            r0.u[2] = tobf(x1.x) | (tobf(x1.y) << 16);
            r0.u[3] = tobf(x1.z) | (tobf(x1.w) << 16);
            r1.u[0] = tobf(y0.x) | (tobf(y0.y) << 16);
            r1.u[1] = tobf(y0.z) | (tobf(y0.w) << 16);
            r1.u[2] = tobf(y1.x) | (tobf(y1.y) << 16);
            r1.u[3] = tobf(y1.z) | (tobf(y1.w) << 16);
            a0 = r0.b; a1 = r1.b;
        } else {
            const unsigned short* p = (const unsigned short*)Aptr + (size_t)arow * HD + quad * 8;
            a0 = *(const bfrag*)p;
            a1 = *(const bfrag*)(p + 32);
        }
        ffrag acc[4];
#pragma unroll
        for (int ft = 0; ft < 4; ft++) {
            acc[ft] = (ffrag){0.f, 0.f, 0.f, 0.f};
            acc[ft] = __builtin_amdgcn_mfma_f32_16x16x32_bf16(a0, wf[ft][0], acc[ft], 0, 0, 0);
            acc[ft] = __builtin_amdgcn_mfma_f32_16x16x32_bf16(a1, wf[ft][1], acc[ft], 0, 0, 0);
        }
        int r0n = tile * 16 + quad * 4;
        float dv[4];
#pragma unroll
        for (int r = 0; r < 4; r++) dv[r] = dinv[min(r0n + r, N - 1)];
#pragma unroll
        for (int ft = 0; ft < 4; ft++)
#pragma unroll
            for (int r = 0; r < 4; r++) {
                int nrow = r0n + r;
                if (nrow < N) {
                    float v = (acc[ft][r] + cbv[ft]) * dv[r];
                    hWs[(size_t)nrow * HD + ft * 16 + m] = (unsigned short)tobf(v);
                }
            }
    }
}

// ---------- aggregation: slot-balanced wave ranges (binary search on rowp),
// 64-slot staging, 8-slot groups (4 unconditional gathers/half), R5 structure.
// Last block does BN finalize + weight fold. ----------
__global__ __launch_bounds__(256) void k_agg(const int* __restrict__ rowp,
                                             const int* __restrict__ ed,
                                             const float* __restrict__ dinv,
                                             const unsigned* __restrict__ hWs,
                                             const float* __restrict__ bias,
                                             const int* __restrict__ batch,
                                             void* __restrict__ outp, int outBf,
                                             float* __restrict__ stats,
                                             float* __restrict__ praw,
                                             int N,
                                             const float* __restrict__ gam,
                                             const float* __restrict__ bet,
                                             float* __restrict__ ss,
                                             const float* __restrict__ Wnext,
                                             unsigned* __restrict__ Wfb,
                                             float* __restrict__ cf,
                                             float invN, int* __restrict__ ticket) {
    int tid = threadIdx.x;
    int lane = tid & 63;
    int hf = lane >> 5;
    int m = lane & 31;
    int wid = blockIdx.x * 4 + (tid >> 6);
    float b0 = bias[2 * m], b1 = bias[2 * m + 1];
    float bs0 = 0.f, bs1 = 0.f, bq0 = 0.f, bq1 = 0.f;
    int curb = -1;
    float p0 = 0.f, p1 = 0.f;

    int total = rowp[N];
    int S = (((total + NWAVES - 1) >> 13) + 7) & ~7;  // slots per wave, mult of 8
    int t0s = wid * S;
    int t1s = t0s + S;
    // lower_bound(rowp, target)
    int i0, i1;
    {
        int lo = 0, hi = N;
        while (lo < hi) { int mid = (lo + hi) >> 1; if (rowp[mid] < t0s) lo = mid + 1; else hi = mid; }
        i0 = lo;
        lo = i0; hi = N;
        while (lo < hi) { int mid = (lo + hi) >> 1; if (rowp[mid] < t1s) lo = mid + 1; else hi = mid; }
        i1 = lo;
    }
    if (i0 < i1) {
        int sb = rowp[i0];
        int send = rowp[i1];
        int i = i0;
        int rem = (rowp[i0 + 1] - sb) >> 3;
        float acc0 = 0.f, acc1 = 0.f;
        for (; sb < send; sb += 64) {
            int eidx = ed[sb + lane];
            int ng = min(8, (send - sb) >> 3);
            for (int g = 0; g < ng; g++) {
                unsigned u[4];
#pragma unroll
                for (int jj = 0; jj < 4; jj++) {
                    int s = __shfl(eidx, (g << 3) + 2 * jj + hf);
                    u[jj] = hWs[(size_t)s * 32 + m];
                }
#pragma unroll
                for (int jj = 0; jj < 4; jj++) {
                    acc0 += bf_lo(u[jj]);
                    acc1 += bf_hi(u[jj]);
                }
                if (--rem == 0) {  // node i complete (wave-uniform)
                    float s0 = acc0 + __shfl_xor(acc0, 32);
                    float s1 = acc1 + __shfl_xor(acc1, 32);
                    float di = dinv[i];
                    float h0 = fmaxf(fmaf(di, s0, b0), 0.f);
                    float h1 = fmaxf(fmaf(di, s1, b1), 0.f);
                    int b = batch[i];
                    if (lane < 32) {
                        if (outBf) ((unsigned*)outp)[(size_t)i * 32 + m] = tobf(h0) | (tobf(h1) << 16);
                        else ((float2*)outp)[(size_t)i * 32 + m] = make_float2(h0, h1);
                        bs0 += h0; bs1 += h1;
                        bq0 = fmaf(h0, h0, bq0); bq1 = fmaf(h1, h1, bq1);
                        if (b != curb) {
                            if (curb >= 0) {
                                atomicAdd(&praw[(size_t)curb * HD + 2 * m], p0);
                                atomicAdd(&praw[(size_t)curb * HD + 2 * m + 1], p1);
                            }
                            curb = b; p0 = h0; p1 = h1;
                        } else { p0 += h0; p1 += h1; }
                    }
                    i++;
                    rem = (i < i1) ? ((rowp[i + 1] - rowp[i]) >> 3) : 0x3fffffff;
                    acc0 = 0.f; acc1 = 0.f;
                }
            }
        }
    }
    if (lane < 32 && curb >= 0) {
        atomicAdd(&praw[(size_t)curb * HD + 2 * m], p0);
        atomicAdd(&praw[(size_t)curb * HD + 2 * m + 1], p1);
    }
    __shared__ float r1s[4][HD], r2s[4][HD];
    int wv = tid >> 6;
    if (lane < 32) {
        r1s[wv][2 * m] = bs0; r1s[wv][2 * m + 1] = bs1;
        r2s[wv][2 * m] = bq0; r2s[wv][2 * m + 1] = bq1;
    }
    __syncthreads();
    if (tid < HD) {
        atomicAdd(&stats[tid], r1s[0][tid] + r1s[1][tid] + r1s[2][tid] + r1s[3][tid]);
        atomicAdd(&stats[HD + tid], r2s[0][tid] + r2s[1][tid] + r2s[2][tid] + r2s[3][tid]);
    }
    // ---- last block: BN finalize + fold into next layer's weights ----
    __shared__ int lastFlag;
    __syncthreads();
    if (tid == 0) {
        __threadfence();
        lastFlag = (atomicAdd(ticket, 1) == (int)gridDim.x - 1) ? 1 : 0;
    }
    __syncthreads();
    if (lastFlag) {
        __shared__ float lss[128];
        if (tid < HD) {
            float s1v = atomicAdd(&stats[tid], 0.f);
            float s2v = atomicAdd(&stats[HD + tid], 0.f);
            float mean = s1v * invN;
            float var = s2v * invN - mean * mean;
            float sc = gam[tid] * rsqrtf(var + BN_EPS);
            float sh = bet[tid] - mean * sc;
            ss[tid] = sc; ss[64 + tid] = sh;
            lss[tid] = sc; lss[64 + tid] = sh;
        }
        __syncthreads();
        if (Wnext && tid < HD) {
            float c = 0.f;
            for (int qq = 0; qq < 32; qq++) {
                float wa = Wnext[tid * HD + 2 * qq];
                float wb = Wnext[tid * HD + 2 * qq + 1];
                Wfb[tid * 32 + qq] = tobf(wa * lss[2 * qq]) | (tobf(wb * lss[2 * qq + 1]) << 16);
                c = fmaf(lss[64 + 2 * qq], wa, c);
                c = fmaf(lss[64 + 2 * qq + 1], wb, c);
            }
            cf[tid] = c;
        }
    }
}

// fused: normalize final h in place (float4) + pool finalize
__global__ __launch_bounds__(256) void k_fin(float* __restrict__ h,
                                             const float* __restrict__ ss_all,
                                             const float* __restrict__ praw,
                                             const int* __restrict__ cnt,
                                             float* __restrict__ pool,
                                             int nquads, int G) {
    int nb1 = (nquads + 255) >> 8;
    if ((int)blockIdx.x < nb1) {
        int idx = blockIdx.x * 256 + threadIdx.x;
        if (idx >= nquads) return;
        const float* ss = ss_all + 2 * 128;
        float4* h4 = (float4*)h;
        float4 v = h4[idx];
        int f0 = (idx * 4) & 63;
        v.x = fmaf(v.x, ss[f0 + 0], ss[64 + f0 + 0]);
        v.y = fmaf(v.y, ss[f0 + 1], ss[64 + f0 + 1]);
        v.z = fmaf(v.z, ss[f0 + 2], ss[64 + f0 + 2]);
        v.w = fmaf(v.w, ss[f0 + 3], ss[64 + f0 + 3]);
        h4[idx] = v;
    } else {
        int idx = (blockIdx.x - nb1) * 256 + threadIdx.x;
        if (idx >= G * 192) return;
        int g = idx / 192;
        int r = idx - g * 192;
        int l = r >> 6;
        int f = r & 63;
        const float* ss = ss_all + l * 128;
        float v = praw[((size_t)l * G + g) * HD + f];
        pool[idx] = fmaf(ss[f], v, (float)cnt[g] * ss[64 + f]);
    }
}

extern "C" void kernel_launch(void* const* d_in, const int* in_sizes, int n_in,
                              void* d_out, int out_size, void* d_ws, size_t ws_size,
                              hipStream_t stream) {
    const int N = in_sizes[0] / HD;             // 100000
    const int E = in_sizes[1] / 2;              // 1000000
    const int G = (out_size - N * HD) / 192;    // 512

    const float* x = (const float*)d_in[0];
    const int* ei = (const int*)d_in[1];
    const int* srcA = ei;
    const int* dstA = ei + E;
    const int* batch = (const int*)d_in[2];
    const float* W[3]    = {(const float*)d_in[3], (const float*)d_in[7],  (const float*)d_in[11]};
    const float* bias[3] = {(const float*)d_in[4], (const float*)d_in[8],  (const float*)d_in[12]};
    const float* gam[3]  = {(const float*)d_in[5], (const float*)d_in[9],  (const float*)d_in[13]};
    const float* bet[3]  = {(const float*)d_in[6], (const float*)d_in[10], (const float*)d_in[14]};

    char* ws = (char*)d_ws;
    size_t off = 0;
    auto alloc = [&](size_t bytes) -> void* {
        void* p = ws + off;
        off = (off + bytes + 255) & ~(size_t)255;
        return p;
    };
    // zero-region (single memset): deg, cur, stats, tickets, praw
    int* deg     = (int*)alloc((size_t)N * 4);
    int* cur     = (int*)alloc((size_t)N * 4);
    float* stats = (float*)alloc(3 * 128 * 4);
    int* tickets = (int*)alloc(3 * 4);
    float* praw  = (float*)alloc((size_t)3 * G * HD * 4);
    size_t zbytes = off;
    float* dinv  = (float*)alloc((size_t)N * 4);
    int* rowp    = (int*)alloc((size_t)(N + 1) * 4);
    int* incl    = (int*)alloc((size_t)N * 4);
    int* bsums   = (int*)alloc(512 * 4);
    int* ed      = (int*)alloc(((size_t)E + 8 * (size_t)N) * 4 + 512);
    unsigned short* hWs  = (unsigned short*)alloc((size_t)(N + 1) * HD * 2);
    unsigned short* hraw = (unsigned short*)alloc((size_t)N * HD * 2);
    float* ss    = (float*)alloc(3 * 128 * 4);
    unsigned* Wfb = (unsigned*)alloc(2 * HD * 32 * 4);
    float* cf    = (float*)alloc(2 * HD * 4);
    int* gcnt    = (int*)alloc((size_t)G * 4);
    (void)ws_size;

    float* pool = (float*)d_out;                      // [G,192]
    float* hbuf = (float*)d_out + (size_t)G * 192;    // [N,64] final h (fp32)

    hipMemsetAsync(deg, 0, zbytes, stream);

    int nb = (N + 255) / 256;
    k_deg<<<(E + 255) / 256, 256, 0, stream>>>(dstA, deg, E);
    k_scan1<<<nb, 256, 0, stream>>>(deg, incl, bsums, dinv, (unsigned*)hWs, N);
    k_scan3<<<nb, 256, 0, stream>>>(rowp, deg, incl, bsums, ed, N, nb);
    k_fill<<<(E + 255) / 256, 256, 0, stream>>>(srcA, dstA, rowp, cur, ed, batch, gcnt, E, N, G);

    const int AGG_BLOCKS = NWAVES / 4;
    const int ntiles = (N + 15) / 16;

    for (int l = 0; l < 3; l++) {
        if (l == 0)
            k_gemm2<1><<<640, 256, 0, stream>>>(x, W[0], nullptr, dinv, hWs, N, ntiles);
        else
            k_gemm2<0><<<640, 256, 0, stream>>>(hraw, Wfb + (size_t)(l - 1) * HD * 32,
                                                cf + (l - 1) * HD, dinv, hWs, N, ntiles);
        void* outp = (l < 2) ? (void*)hraw : (void*)hbuf;
        k_agg<<<AGG_BLOCKS, 256, 0, stream>>>(rowp, ed, dinv, (const unsigned*)hWs,
                                              bias[l], batch, outp, (l < 2) ? 1 : 0,
                                              stats + l * 128, praw + (size_t)l * G * HD,
                                              N,
                                              gam[l], bet[l], ss + l * 128,
                                              (l < 2) ? W[l + 1] : nullptr,
                                              Wfb + (size_t)(l < 2 ? l : 0) * HD * 32,
                                              cf + (l < 2 ? l : 0) * HD,
                                              1.0f / (float)N, tickets + l);
    }
    int nquads = N * HD / 4;
    int nb1 = (nquads + 255) / 256;
    int nb2 = (G * 192 + 255) / 256;
    k_fin<<<nb1 + nb2, 256, 0, stream>>>(hbuf, ss, praw, gcnt, pool, nquads, G);
}